// Round 18
// baseline (525.857 us; speedup 1.0000x reference)
//
#include <hip/hip_runtime.h>

typedef unsigned short u16;
typedef float f32x4 __attribute__((ext_vector_type(4)));
typedef float f32x2 __attribute__((ext_vector_type(2)));
typedef short bf16x8 __attribute__((ext_vector_type(8)));
typedef u16 u16x4 __attribute__((ext_vector_type(4)));
typedef unsigned int uint2v __attribute__((ext_vector_type(2)));

// B=2, C=64, D=3, N=4096, K=16, E=128, H=256

static __device__ __forceinline__ u16 f2bf(float x) {
    union { float f; unsigned int u; } v; v.f = x;
    unsigned int u = v.u;
    unsigned int r = u + 0x7fffu + ((u >> 16) & 1u);   // RNE
    return (u16)(r >> 16);
}

static __device__ __forceinline__ float bf2f(u16 h) {
    union { unsigned int u; float f; } v; v.u = ((unsigned int)h) << 16;
    return v.f;
}

// packed RNE f32x2 -> bf16x2: single v_cvt_pk_bf16_f32 when available
#if __has_builtin(__builtin_amdgcn_cvt_pk_bf16_f32)
typedef __bf16 bf16x2t __attribute__((ext_vector_type(2)));
static __device__ __forceinline__ unsigned int pk2(float a, float b) {
    bf16x2t t = __builtin_amdgcn_cvt_pk_bf16_f32(a, b);   // lo=a, hi=b, RNE
    unsigned int u;
    __builtin_memcpy(&u, &t, 4);
    return u;
}
#else
static __device__ __forceinline__ unsigned int pk2(float a, float b) {
    return (unsigned int)f2bf(a) | ((unsigned int)f2bf(b) << 16);
}
#endif

// -------- mean over D + bf16 copies of x/pc + weight prep (blocks 0..255) ---
__global__ __launch_bounds__(256) void mean_kernel(const float* __restrict__ x,
                                                   float* __restrict__ pc,
                                                   const float* __restrict__ W1,
                                                   const float* __restrict__ W2,
                                                   const float* __restrict__ W3,
                                                   u16* __restrict__ W2bf,
                                                   u16* __restrict__ W3bf,
                                                   u16* __restrict__ W1dTbf,
                                                   u16* __restrict__ W1bTbf,
                                                   u16* __restrict__ xbf,
                                                   u16* __restrict__ pcbf) {
    int t = blockIdx.x * 256 + threadIdx.x;            // over B*C*N = 524288
    int n = t & 4095;
    int bc = t >> 12;
    const float* xp = x + bc * 3 * 4096 + n;
    float x0 = xp[0], x1 = xp[4096], x2 = xp[8192];
    float m = (x0 + x1 + x2) / 3.0f;
    pc[t] = m;
    pcbf[t] = f2bf(m);
    int xb = bc * 3 * 4096 + n;
    xbf[xb] = f2bf(x0);
    xbf[xb + 4096] = f2bf(x1);
    xbf[xb + 8192] = f2bf(x2);

    if (t < 65536) {                                   // prep (blocks 0..255)
        W2bf[t] = f2bf(W2[t]);
        if (t < 16384) {
            W3bf[t] = f2bf(W3[t]);
            int c = t >> 8, h = t & 255;
            float wa = W1[h * 128 + c];
            float wb = W1[h * 128 + 64 + c];
            W1dTbf[h * 64 + c] = f2bf(wa - wb);        // [h][c] bf16
            W1bTbf[h * 64 + c] = f2bf(wb);             // [h][c] bf16
        }
    }
}

// Branch-free sorted insert: exact fp32 compare, ~5 VALU/step, no divergence.
#define INSERT(dist, idxv) do { \
    float _v = (dist); int _vi = (idxv); \
    _Pragma("unroll") \
    for (int _s = 0; _s < 16; ++_s) { \
        bool _c = _v < bd[_s]; \
        float _nb = _c ? _v : bd[_s]; \
        float _nv = _c ? bd[_s] : _v; \
        int _nbi = _c ? _vi : bi[_s]; \
        int _nvi = _c ? bi[_s] : _vi; \
        bd[_s] = _nb; _v = _nv; bi[_s] = _nbi; _vi = _nvi; \
    } } while (0)

// ---------------- KNN phase 1: per-chunk top-16 (computes sq inline) --------
// R14/R16 structure (CH=32, 1024 blocks, single staged tile, qv in registers).
// Dot products use packed v_pk_fma_f32 (f32x2 elementwise fma — IEEE-exact per
// component, bit-identical to scalar fmaf): dot instrs 8192 -> 4096 per thread.
// pi stored u16 (indices < 4096).
__global__ __launch_bounds__(256, 3) void knn_part_kernel(const float* __restrict__ pc,
                                                          float* __restrict__ pd,
                                                          u16* __restrict__ pi) {
    __shared__ float ptile[64][128];
    __shared__ float sqt[128];
    int tid = threadIdx.x;
    int bid = blockIdx.x;
    int ch = bid & 31, qb = (bid >> 5) & 15, b = bid >> 9;
    int n = qb * 256 + tid;
    int m0 = ch * 128;

    #pragma unroll
    for (int it = 0; it < 8; ++it) {
        int lin4 = it * 256 + tid;                     // 2048 float4s
        int c = lin4 >> 5, mm4 = (lin4 & 31) * 4;
        *(float4*)&ptile[c][mm4] =
            *(const float4*)&pc[(b * 64 + c) * 4096 + m0 + mm4];
    }
    __syncthreads();
    if (tid < 128) {                                   // candidate norms from tile
        float s = 0.f;
        #pragma unroll
        for (int c = 0; c < 64; ++c) {
            float v = ptile[c][tid];
            s = fmaf(v, v, s);
        }
        sqt[tid] = s;
    }

    float qv[64];
    float sqn = 0.f;
    #pragma unroll
    for (int c = 0; c < 64; ++c) {
        qv[c] = pc[(b * 64 + c) * 4096 + n];
        sqn = fmaf(qv[c], qv[c], sqn);
    }

    float bd[16]; int bi[16];
    #pragma unroll
    for (int s = 0; s < 16; ++s) { bd[s] = 3.4e38f; bi[s] = 0; }
    __syncthreads();

    for (int mb = 0; mb < 128; mb += 4) {
        f32x2 d01 = (f32x2){0.f, 0.f};
        f32x2 d23 = (f32x2){0.f, 0.f};
        #pragma unroll
        for (int c = 0; c < 64; ++c) {
            float4 pv = *(const float4*)&ptile[c][mb];
            f32x2 qc2 = (f32x2){qv[c], qv[c]};
#if __has_builtin(__builtin_elementwise_fma)
            d01 = __builtin_elementwise_fma(qc2, (f32x2){pv.x, pv.y}, d01);
            d23 = __builtin_elementwise_fma(qc2, (f32x2){pv.z, pv.w}, d23);
#else
            d01[0] = fmaf(qv[c], pv.x, d01[0]);
            d01[1] = fmaf(qv[c], pv.y, d01[1]);
            d23[0] = fmaf(qv[c], pv.z, d23[0]);
            d23[1] = fmaf(qv[c], pv.w, d23[1]);
#endif
        }
        int m = m0 + mb;
        float e0 = (sqn - 2.f * d01[0]) + sqt[mb + 0]; if (m + 0 == n) e0 = 3.4e38f;
        float e1 = (sqn - 2.f * d01[1]) + sqt[mb + 1]; if (m + 1 == n) e1 = 3.4e38f;
        float e2 = (sqn - 2.f * d23[0]) + sqt[mb + 2]; if (m + 2 == n) e2 = 3.4e38f;
        float e3 = (sqn - 2.f * d23[1]) + sqt[mb + 3]; if (m + 3 == n) e3 = 3.4e38f;
        INSERT(e0, m + 0);
        INSERT(e1, m + 1);
        INSERT(e2, m + 2);
        INSERT(e3, m + 3);
    }
    int base = ((b * 4096 + n) * 32 + ch) * 16;
    #pragma unroll
    for (int s = 0; s < 16; ++s) { pd[base + s] = bd[s]; pi[base + s] = (u16)bi[s]; }
}

// ---------------- KNN phase 2: wave-per-query extract-min x16 ----------------
__global__ __launch_bounds__(256) void knn_merge_kernel(const float* __restrict__ pd,
                                                        const u16* __restrict__ pi,
                                                        int* __restrict__ idxw) {
    int tid = threadIdx.x;
    int lane = tid & 63;
    int q = blockIdx.x * 4 + (tid >> 6);               // 2048 blocks, 4 queries each
    int base = q * 512;

    float d[8]; int ix[8];
    #pragma unroll
    for (int j = 0; j < 8; ++j) {
        d[j] = pd[base + lane + 64 * j];
        ix[j] = (int)pi[base + lane + 64 * j];
    }

    for (int e = 0; e < 16; ++e) {
        float lmd = d[0]; int lmi = ix[0];
        #pragma unroll
        for (int j = 1; j < 8; ++j) {
            bool c = d[j] < lmd;
            lmd = c ? d[j] : lmd;
            lmi = c ? ix[j] : lmi;
        }
        float wm = lmd;
        #pragma unroll
        for (int off = 32; off; off >>= 1)
            wm = fminf(wm, __shfl_xor(wm, off));
        unsigned long long msk = __ballot(lmd == wm);
        int L = (int)__ffsll(msk) - 1;
        int wmi = __shfl(lmi, L);
        if (lane == 0) idxw[q * 16 + e] = wmi;
        if (lane == L) {
            #pragma unroll
            for (int j = 0; j < 8; ++j)
                if (ix[j] == wmi) d[j] = 3.4e38f;
        }
    }
}

// ------------- qp via MFMA: Qbf = W1b@pc, Pbf = (W1a-W1b)@x + b1 -------------
// 512 blocks x 256 thr. Block covers 64 output columns; wave w -> 16 cols.
__global__ __launch_bounds__(256) void qp_mfma_kernel(const u16* __restrict__ xbf,
                                                      const u16* __restrict__ pcbf,
                                                      const u16* __restrict__ W1dTbf,
                                                      const u16* __restrict__ W1bTbf,
                                                      const float* __restrict__ b1,
                                                      u16* __restrict__ Qbf,
                                                      u16* __restrict__ Pbf) {
    int tid = threadIdx.x, bid = blockIdx.x;
    int w = tid >> 6, lane = tid & 63, cl = lane & 15, q = lane >> 4;

    const u16* Wt;
    const u16* src;
    u16* dst;
    int cstride;
    bool isP;
    if (bid < 128) {                                   // Q: 8192 m-cols
        int lin = bid * 64;
        int b = lin >> 12, m0 = lin & 4095;
        Wt = W1bTbf;
        dst = Qbf + (b * 4096 + m0) * 256;
        src = pcbf + b * 64 * 4096 + m0;
        cstride = 4096;
        isP = false;
    } else {                                           // P: 24576 (b,d,n)-cols
        int lin = (bid - 128) * 64;
        int b = lin / 12288;
        int r = lin % 12288;
        int d = r >> 12, n0 = r & 4095;
        Wt = W1dTbf;
        dst = Pbf + ((b * 3 + d) * 4096 + n0) * 256;
        src = xbf + ((b * 64) * 3 + d) * 4096 + n0;
        cstride = 3 * 4096;
        isP = true;
    }
    int cw = w * 16;

    bf16x8 bfr[2];
    #pragma unroll
    for (int kh = 0; kh < 2; ++kh)
        #pragma unroll
        for (int j = 0; j < 8; ++j) {
            int c = kh * 32 + q * 8 + j;
            bfr[kh][j] = (short)src[c * cstride + cw + cl];
        }

    #pragma unroll
    for (int ht = 0; ht < 16; ++ht) {
        f32x4 acc = (f32x4){0.f, 0.f, 0.f, 0.f};
        const u16* arow = Wt + (ht * 16 + cl) * 64 + q * 8;
        bf16x8 a0 = *(const bf16x8*)arow;
        bf16x8 a1 = *(const bf16x8*)(arow + 32);
        acc = __builtin_amdgcn_mfma_f32_16x16x32_bf16(a0, bfr[0], acc, 0, 0, 0);
        acc = __builtin_amdgcn_mfma_f32_16x16x32_bf16(a1, bfr[1], acc, 0, 0, 0);
        uint2v o;
        if (isP) {
            float4 bv = *(const float4*)(b1 + ht * 16 + q * 4);
            o[0] = pk2(acc[0] + bv.x, acc[1] + bv.y);
            o[1] = pk2(acc[2] + bv.z, acc[3] + bv.w);
        } else {
            o[0] = pk2(acc[0], acc[1]);
            o[1] = pk2(acc[2], acc[3]);
        }
        *(uint2v*)&dst[(cw + cl) * 256 + ht * 16 + q * 4] = o;
    }
}

// ---------------- fused layer2+layer3+maxK+residual (bf16 MFMA) ----------------
// R12/R14/R16 proven body (133 us): 8-wave blocks, 2 points/block, 96x264 hL,
// grid 4096. Layer2: wave w -> rows w*32 (acc[2][6]). Layer3 rows x col-half.
// XCD-contiguous n swizzle. pk2 = hardware v_cvt_pk_bf16_f32.
__global__ __launch_bounds__(512) void fused_mlp_kernel(const float* __restrict__ x,
                                                        const u16* __restrict__ Pbf,
                                                        const u16* __restrict__ Qbf,
                                                        const int* __restrict__ idxw,
                                                        const u16* __restrict__ W2bf,
                                                        const u16* __restrict__ W3bf,
                                                        const float* __restrict__ b2,
                                                        const float* __restrict__ b3,
                                                        float* __restrict__ out) {
    __shared__ u16 hL[96][264];                        // stride 264: 16B-aligned, 2-way banks

    int tid = threadIdx.x;
    int bid = blockIdx.x;                              // 4096
    int b = bid >> 11;
    int rr = bid & 2047;
    int n0 = (((rr & 7) << 8) | (rr >> 3)) << 1;       // xcd-contiguous mapping

    int w = tid >> 6, lane = tid & 63;
    int cl = lane & 15, q = lane >> 4;

    // ---- build h1 = relu(P + Q) into LDS (bf16) ----
    // wave w: point g = w&1, k-range kh..kh+3 (kh = (w>>1)*4); lane = h-chunk.
    {
        int g = w & 1, kh = (w >> 1) * 4;
        int n = n0 + g;
        u16x4 pv[3];
        #pragma unroll
        for (int d = 0; d < 3; ++d)
            pv[d] = *(const u16x4*)&Pbf[((b * 3 + d) * 4096 + n) * 256 + lane * 4];
        const int* idq = idxw + (b * 4096 + n) * 16 + kh;
        #pragma unroll
        for (int kk = 0; kk < 4; ++kk) {
            int m = idq[kk];                           // wave-uniform
            u16x4 qv = *(const u16x4*)&Qbf[(b * 4096 + m) * 256 + lane * 4];
            float q0 = bf2f(qv[0]), q1 = bf2f(qv[1]), q2 = bf2f(qv[2]), q3 = bf2f(qv[3]);
            #pragma unroll
            for (int d = 0; d < 3; ++d) {
                uint2v hv;
                hv[0] = pk2(fmaxf(bf2f(pv[d][0]) + q0, 0.f), fmaxf(bf2f(pv[d][1]) + q1, 0.f));
                hv[1] = pk2(fmaxf(bf2f(pv[d][2]) + q2, 0.f), fmaxf(bf2f(pv[d][3]) + q3, 0.f));
                *(uint2v*)&hL[g * 48 + d * 16 + kh + kk][lane * 4] = hv;
            }
        }
    }
    __syncthreads();

    // ---- layer 2: h2 = relu(W2 @ h1 + b2), 256 rows x 96 cols ----
    // wave w -> rows w*32 .. w*32+31 (2 row-tiles)
    f32x4 acc[2][6];
    #pragma unroll
    for (int i = 0; i < 2; ++i)
        #pragma unroll
        for (int jt = 0; jt < 6; ++jt)
            acc[i][jt] = (f32x4){0.f, 0.f, 0.f, 0.f};

    const u16* Arow = W2bf + (w * 32 + cl) * 256 + q * 8;
    for (int kt = 0; kt < 8; ++kt) {
        int k0 = kt * 32;
        bf16x8 a[2], bb[6];
        #pragma unroll
        for (int i = 0; i < 2; ++i)
            a[i] = *(const bf16x8*)(Arow + i * 4096 + k0);
        #pragma unroll
        for (int jt = 0; jt < 6; ++jt)
            bb[jt] = *(const bf16x8*)(&hL[jt * 16 + cl][k0 + q * 8]);
        #pragma unroll
        for (int i = 0; i < 2; ++i)
            #pragma unroll
            for (int jt = 0; jt < 6; ++jt)
                acc[i][jt] = __builtin_amdgcn_mfma_f32_16x16x32_bf16(a[i], bb[jt], acc[i][jt], 0, 0, 0);
    }
    __syncthreads();   // everyone done reading h1

    // write h2 (bf16) into the same LDS buffer; bias from L1
    #pragma unroll
    for (int i = 0; i < 2; ++i) {
        int rowb = w * 32 + i * 16 + q * 4;
        float4 bv = *(const float4*)(b2 + rowb);
        #pragma unroll
        for (int jt = 0; jt < 6; ++jt) {
            f32x4 v = acc[i][jt];
            uint2v hv;
            hv[0] = pk2(fmaxf(v[0] + bv.x, 0.f), fmaxf(v[1] + bv.y, 0.f));
            hv[1] = pk2(fmaxf(v[2] + bv.z, 0.f), fmaxf(v[3] + bv.w, 0.f));
            *(uint2v*)&hL[jt * 16 + cl][rowb] = hv;
        }
    }
    __syncthreads();

    // ---- layer 3: r = W3 @ h2 + b3, 64 rows x 96 cols ----
    // wave w -> rows (w&3)*16.., col-half jt0 = (w>>2)*3 (3 of 6 tiles)
    int rw = (w & 3) * 16, jt0 = (w >> 2) * 3;
    f32x4 acc3[3];
    #pragma unroll
    for (int jt = 0; jt < 3; ++jt) acc3[jt] = (f32x4){0.f, 0.f, 0.f, 0.f};

    const u16* A3row = W3bf + (rw + cl) * 256 + q * 8;
    for (int kt = 0; kt < 8; ++kt) {
        int k0 = kt * 32;
        bf16x8 a3 = *(const bf16x8*)(A3row + k0);
        #pragma unroll
        for (int jt = 0; jt < 3; ++jt) {
            bf16x8 bb = *(const bf16x8*)(&hL[(jt0 + jt) * 16 + cl][k0 + q * 8]);
            acc3[jt] = __builtin_amdgcn_mfma_f32_16x16x32_bf16(a3, bb, acc3[jt], 0, 0, 0);
        }
    }

    // ---- epilogue: +b3, max over k (16 cols of each tile = cl), +x, store ----
    int rowb = rw + q * 4;
    float4 b3v = *(const float4*)(b3 + rowb);
    #pragma unroll
    for (int jt = 0; jt < 3; ++jt) {
        int jj = jt0 + jt;
        int g = jj / 3, d = jj % 3;
        int n = n0 + g;
        f32x4 v = acc3[jt];
        v[0] += b3v.x;
        v[1] += b3v.y;
        v[2] += b3v.z;
        v[3] += b3v.w;
        #pragma unroll
        for (int off = 1; off < 16; off <<= 1) {
            v[0] = fmaxf(v[0], __shfl_xor(v[0], off));
            v[1] = fmaxf(v[1], __shfl_xor(v[1], off));
            v[2] = fmaxf(v[2], __shfl_xor(v[2], off));
            v[3] = fmaxf(v[3], __shfl_xor(v[3], off));
        }
        if (cl == 0) {
            #pragma unroll
            for (int r = 0; r < 4; ++r) {
                int addr = ((b * 64 + rowb + r) * 3 + d) * 4096 + n;
                out[addr] = v[r] + x[addr];
            }
        }
    }
}

extern "C" void kernel_launch(void* const* d_in, const int* in_sizes, int n_in,
                              void* d_out, int out_size, void* d_ws, size_t ws_size,
                              hipStream_t stream) {
    (void)in_sizes; (void)n_in; (void)out_size; (void)ws_size;
    const float* x  = (const float*)d_in[0];
    const float* W1 = (const float*)d_in[1];
    const float* b1 = (const float*)d_in[2];
    const float* W2 = (const float*)d_in[3];
    const float* b2 = (const float*)d_in[4];
    const float* W3 = (const float*)d_in[5];
    const float* b3 = (const float*)d_in[6];
    float* out = (float*)d_out;

    char* ws = (char*)d_ws;
    float* pc     = (float*)(ws + 0);          // 2,097,152 B  (B,C,N) fp32
    int*   idxw   = (int*)  (ws + 2129920);    //   524,288 B  (B,N,K)
    u16*   Qbf    = (u16*)  (ws + 2654208);    // 4,194,304 B  (B,N,H) bf16
    u16*   Pbf    = (u16*)  (ws + 6848512);    // 12,582,912 B (B,D,N,H) bf16
    u16*   W2bf   = (u16*)  (ws + 19431424);   //   131,072 B
    u16*   W3bf   = (u16*)  (ws + 19562496);   //    32,768 B
    u16*   W1dTbf = (u16*)  (ws + 19595264);   //    32,768 B  [h][c]
    u16*   W1bTbf = (u16*)  (ws + 19628032);   //    32,768 B  [h][c]
    u16*   xbf    = (u16*)  (ws + 19660800);   // 6,291,456 B  (B,C,D,N) bf16
    u16*   pcbf   = (u16*)  (ws + 25952256);   // 2,097,152 B  (B,C,N) bf16
    // KNN partials: pd fp32 (16,777,216 B) aliases Qbf+Pbf exactly (written by
    // knn_part, read by merge, BEFORE qp writes Qbf/Pbf). pi stored u16
    // (8,388,608 B) after pcbf; ends 36,438,016 < proven ws limit 36,503,552.
    float* pd     = (float*)(ws + 2654208);    // ends 19,431,424
    u16*   pi     = (u16*)  (ws + 28049408);   // ends 36,438,016

    mean_kernel<<<2048, 256, 0, stream>>>(x, pc, W1, W2, W3, W2bf, W3bf,
                                          W1dTbf, W1bTbf, xbf, pcbf);
    knn_part_kernel<<<1024, 256, 0, stream>>>(pc, pd, pi);
    knn_merge_kernel<<<2048, 256, 0, stream>>>(pd, pi, idxw);
    qp_mfma_kernel<<<512, 256, 0, stream>>>(xbf, pcbf, W1dTbf, W1bTbf, b1, Qbf, Pbf);
    fused_mlp_kernel<<<4096, 512, 0, stream>>>(x, Pbf, Qbf, idxw, W2bf, W3bf, b2, b3, out);
}

// Round 19
// 324.284 us; speedup vs baseline: 1.6216x; 1.6216x over previous
//
#include <hip/hip_runtime.h>

typedef unsigned short u16;
typedef float f32x4 __attribute__((ext_vector_type(4)));
typedef short bf16x8 __attribute__((ext_vector_type(8)));
typedef u16 u16x4 __attribute__((ext_vector_type(4)));
typedef unsigned int uint2v __attribute__((ext_vector_type(2)));

// B=2, C=64, D=3, N=4096, K=16, E=128, H=256

static __device__ __forceinline__ u16 f2bf(float x) {
    union { float f; unsigned int u; } v; v.f = x;
    unsigned int u = v.u;
    unsigned int r = u + 0x7fffu + ((u >> 16) & 1u);   // RNE
    return (u16)(r >> 16);
}

static __device__ __forceinline__ float bf2f(u16 h) {
    union { unsigned int u; float f; } v; v.u = ((unsigned int)h) << 16;
    return v.f;
}

// packed RNE f32x2 -> bf16x2: single v_cvt_pk_bf16_f32 when available
#if __has_builtin(__builtin_amdgcn_cvt_pk_bf16_f32)
typedef __bf16 bf16x2t __attribute__((ext_vector_type(2)));
static __device__ __forceinline__ unsigned int pk2(float a, float b) {
    bf16x2t t = __builtin_amdgcn_cvt_pk_bf16_f32(a, b);   // lo=a, hi=b, RNE
    unsigned int u;
    __builtin_memcpy(&u, &t, 4);
    return u;
}
#else
static __device__ __forceinline__ unsigned int pk2(float a, float b) {
    return (unsigned int)f2bf(a) | ((unsigned int)f2bf(b) << 16);
}
#endif

// -------- mean over D + bf16 copies of x/pc + weight prep (blocks 0..255) ---
__global__ __launch_bounds__(256) void mean_kernel(const float* __restrict__ x,
                                                   float* __restrict__ pc,
                                                   const float* __restrict__ W1,
                                                   const float* __restrict__ W2,
                                                   const float* __restrict__ W3,
                                                   u16* __restrict__ W2bf,
                                                   u16* __restrict__ W3bf,
                                                   u16* __restrict__ W1dTbf,
                                                   u16* __restrict__ W1bTbf,
                                                   u16* __restrict__ xbf,
                                                   u16* __restrict__ pcbf) {
    int t = blockIdx.x * 256 + threadIdx.x;            // over B*C*N = 524288
    int n = t & 4095;
    int bc = t >> 12;
    const float* xp = x + bc * 3 * 4096 + n;
    float x0 = xp[0], x1 = xp[4096], x2 = xp[8192];
    float m = (x0 + x1 + x2) / 3.0f;
    pc[t] = m;
    pcbf[t] = f2bf(m);
    int xb = bc * 3 * 4096 + n;
    xbf[xb] = f2bf(x0);
    xbf[xb + 4096] = f2bf(x1);
    xbf[xb + 8192] = f2bf(x2);

    if (t < 65536) {                                   // prep (blocks 0..255)
        W2bf[t] = f2bf(W2[t]);
        if (t < 16384) {
            W3bf[t] = f2bf(W3[t]);
            int c = t >> 8, h = t & 255;
            float wa = W1[h * 128 + c];
            float wb = W1[h * 128 + 64 + c];
            W1dTbf[h * 64 + c] = f2bf(wa - wb);        // [h][c] bf16
            W1bTbf[h * 64 + c] = f2bf(wb);             // [h][c] bf16
        }
    }
}

// Branch-free sorted insert: exact fp32 compare, ~5 VALU/step, no divergence.
#define INSERT(dist, idxv) do { \
    float _v = (dist); int _vi = (idxv); \
    _Pragma("unroll") \
    for (int _s = 0; _s < 16; ++_s) { \
        bool _c = _v < bd[_s]; \
        float _nb = _c ? _v : bd[_s]; \
        float _nv = _c ? bd[_s] : _v; \
        int _nbi = _c ? _vi : bi[_s]; \
        int _nvi = _c ? bi[_s] : _vi; \
        bd[_s] = _nb; _v = _nv; bi[_s] = _nbi; _vi = _nvi; \
    } } while (0)

// ---------------- KNN phase 1: per-chunk top-16 (computes sq inline) --------
// EXACT R16 body — DO NOT restructure the inner loop. Three attempts (CH=16
// 2-tile loop, sched_barrier fences, f32x2 packed fma) all perturbed register
// allocation and spilled qv[64] to scratch (VGPR 252 -> 76/84, 2-4x slower).
// The fully-unrolled scalar-fmaf form holds qv resident at 252 VGPR,
// 2 waves/SIMD, ~122 us. pi stored u16 (indices < 4096).
__global__ __launch_bounds__(256, 3) void knn_part_kernel(const float* __restrict__ pc,
                                                          float* __restrict__ pd,
                                                          u16* __restrict__ pi) {
    __shared__ float ptile[64][128];
    __shared__ float sqt[128];
    int tid = threadIdx.x;
    int bid = blockIdx.x;
    int ch = bid & 31, qb = (bid >> 5) & 15, b = bid >> 9;
    int n = qb * 256 + tid;
    int m0 = ch * 128;

    #pragma unroll
    for (int it = 0; it < 8; ++it) {
        int lin4 = it * 256 + tid;                     // 2048 float4s
        int c = lin4 >> 5, mm4 = (lin4 & 31) * 4;
        *(float4*)&ptile[c][mm4] =
            *(const float4*)&pc[(b * 64 + c) * 4096 + m0 + mm4];
    }
    __syncthreads();
    if (tid < 128) {                                   // candidate norms from tile
        float s = 0.f;
        #pragma unroll
        for (int c = 0; c < 64; ++c) {
            float v = ptile[c][tid];
            s = fmaf(v, v, s);
        }
        sqt[tid] = s;
    }

    float qv[64];
    float sqn = 0.f;
    #pragma unroll
    for (int c = 0; c < 64; ++c) {
        qv[c] = pc[(b * 64 + c) * 4096 + n];
        sqn = fmaf(qv[c], qv[c], sqn);
    }

    float bd[16]; int bi[16];
    #pragma unroll
    for (int s = 0; s < 16; ++s) { bd[s] = 3.4e38f; bi[s] = 0; }
    __syncthreads();

    for (int mb = 0; mb < 128; mb += 4) {
        float d0 = 0.f, d1 = 0.f, d2 = 0.f, d3 = 0.f;
        #pragma unroll
        for (int c = 0; c < 64; ++c) {
            float4 pv = *(const float4*)&ptile[c][mb];
            float qc = qv[c];
            d0 = fmaf(qc, pv.x, d0);
            d1 = fmaf(qc, pv.y, d1);
            d2 = fmaf(qc, pv.z, d2);
            d3 = fmaf(qc, pv.w, d3);
        }
        int m = m0 + mb;
        float e0 = (sqn - 2.f * d0) + sqt[mb + 0]; if (m + 0 == n) e0 = 3.4e38f;
        float e1 = (sqn - 2.f * d1) + sqt[mb + 1]; if (m + 1 == n) e1 = 3.4e38f;
        float e2 = (sqn - 2.f * d2) + sqt[mb + 2]; if (m + 2 == n) e2 = 3.4e38f;
        float e3 = (sqn - 2.f * d3) + sqt[mb + 3]; if (m + 3 == n) e3 = 3.4e38f;
        INSERT(e0, m + 0);
        INSERT(e1, m + 1);
        INSERT(e2, m + 2);
        INSERT(e3, m + 3);
    }
    int base = ((b * 4096 + n) * 32 + ch) * 16;
    #pragma unroll
    for (int s = 0; s < 16; ++s) { pd[base + s] = bd[s]; pi[base + s] = (u16)bi[s]; }
}

// ---------------- KNN phase 2: wave-per-query extract-min x16 ----------------
__global__ __launch_bounds__(256) void knn_merge_kernel(const float* __restrict__ pd,
                                                        const u16* __restrict__ pi,
                                                        int* __restrict__ idxw) {
    int tid = threadIdx.x;
    int lane = tid & 63;
    int q = blockIdx.x * 4 + (tid >> 6);               // 2048 blocks, 4 queries each
    int base = q * 512;

    float d[8]; int ix[8];
    #pragma unroll
    for (int j = 0; j < 8; ++j) {
        d[j] = pd[base + lane + 64 * j];
        ix[j] = (int)pi[base + lane + 64 * j];
    }

    for (int e = 0; e < 16; ++e) {
        float lmd = d[0]; int lmi = ix[0];
        #pragma unroll
        for (int j = 1; j < 8; ++j) {
            bool c = d[j] < lmd;
            lmd = c ? d[j] : lmd;
            lmi = c ? ix[j] : lmi;
        }
        float wm = lmd;
        #pragma unroll
        for (int off = 32; off; off >>= 1)
            wm = fminf(wm, __shfl_xor(wm, off));
        unsigned long long msk = __ballot(lmd == wm);
        int L = (int)__ffsll(msk) - 1;
        int wmi = __shfl(lmi, L);
        if (lane == 0) idxw[q * 16 + e] = wmi;
        if (lane == L) {
            #pragma unroll
            for (int j = 0; j < 8; ++j)
                if (ix[j] == wmi) d[j] = 3.4e38f;
        }
    }
}

// ------------- qp via MFMA: Qbf = W1b@pc, Pbf = (W1a-W1b)@x + b1 -------------
// 512 blocks x 256 thr. Block covers 64 output columns; wave w -> 16 cols.
__global__ __launch_bounds__(256) void qp_mfma_kernel(const u16* __restrict__ xbf,
                                                      const u16* __restrict__ pcbf,
                                                      const u16* __restrict__ W1dTbf,
                                                      const u16* __restrict__ W1bTbf,
                                                      const float* __restrict__ b1,
                                                      u16* __restrict__ Qbf,
                                                      u16* __restrict__ Pbf) {
    int tid = threadIdx.x, bid = blockIdx.x;
    int w = tid >> 6, lane = tid & 63, cl = lane & 15, q = lane >> 4;

    const u16* Wt;
    const u16* src;
    u16* dst;
    int cstride;
    bool isP;
    if (bid < 128) {                                   // Q: 8192 m-cols
        int lin = bid * 64;
        int b = lin >> 12, m0 = lin & 4095;
        Wt = W1bTbf;
        dst = Qbf + (b * 4096 + m0) * 256;
        src = pcbf + b * 64 * 4096 + m0;
        cstride = 4096;
        isP = false;
    } else {                                           // P: 24576 (b,d,n)-cols
        int lin = (bid - 128) * 64;
        int b = lin / 12288;
        int r = lin % 12288;
        int d = r >> 12, n0 = r & 4095;
        Wt = W1dTbf;
        dst = Pbf + ((b * 3 + d) * 4096 + n0) * 256;
        src = xbf + ((b * 64) * 3 + d) * 4096 + n0;
        cstride = 3 * 4096;
        isP = true;
    }
    int cw = w * 16;

    bf16x8 bfr[2];
    #pragma unroll
    for (int kh = 0; kh < 2; ++kh)
        #pragma unroll
        for (int j = 0; j < 8; ++j) {
            int c = kh * 32 + q * 8 + j;
            bfr[kh][j] = (short)src[c * cstride + cw + cl];
        }

    #pragma unroll
    for (int ht = 0; ht < 16; ++ht) {
        f32x4 acc = (f32x4){0.f, 0.f, 0.f, 0.f};
        const u16* arow = Wt + (ht * 16 + cl) * 64 + q * 8;
        bf16x8 a0 = *(const bf16x8*)arow;
        bf16x8 a1 = *(const bf16x8*)(arow + 32);
        acc = __builtin_amdgcn_mfma_f32_16x16x32_bf16(a0, bfr[0], acc, 0, 0, 0);
        acc = __builtin_amdgcn_mfma_f32_16x16x32_bf16(a1, bfr[1], acc, 0, 0, 0);
        uint2v o;
        if (isP) {
            float4 bv = *(const float4*)(b1 + ht * 16 + q * 4);
            o[0] = pk2(acc[0] + bv.x, acc[1] + bv.y);
            o[1] = pk2(acc[2] + bv.z, acc[3] + bv.w);
        } else {
            o[0] = pk2(acc[0], acc[1]);
            o[1] = pk2(acc[2], acc[3]);
        }
        *(uint2v*)&dst[(cw + cl) * 256 + ht * 16 + q * 4] = o;
    }
}

// ---------------- fused layer2+layer3+maxK+residual (bf16 MFMA) ----------------
// R12/R14/R16 proven body (133 us): 8-wave blocks, 2 points/block, 96x264 hL,
// grid 4096. Layer2: wave w -> rows w*32 (acc[2][6]). Layer3 rows x col-half.
// XCD-contiguous n swizzle. pk2 = hardware v_cvt_pk_bf16_f32.
__global__ __launch_bounds__(512) void fused_mlp_kernel(const float* __restrict__ x,
                                                        const u16* __restrict__ Pbf,
                                                        const u16* __restrict__ Qbf,
                                                        const int* __restrict__ idxw,
                                                        const u16* __restrict__ W2bf,
                                                        const u16* __restrict__ W3bf,
                                                        const float* __restrict__ b2,
                                                        const float* __restrict__ b3,
                                                        float* __restrict__ out) {
    __shared__ u16 hL[96][264];                        // stride 264: 16B-aligned, 2-way banks

    int tid = threadIdx.x;
    int bid = blockIdx.x;                              // 4096
    int b = bid >> 11;
    int rr = bid & 2047;
    int n0 = (((rr & 7) << 8) | (rr >> 3)) << 1;       // xcd-contiguous mapping

    int w = tid >> 6, lane = tid & 63;
    int cl = lane & 15, q = lane >> 4;

    // ---- build h1 = relu(P + Q) into LDS (bf16) ----
    // wave w: point g = w&1, k-range kh..kh+3 (kh = (w>>1)*4); lane = h-chunk.
    {
        int g = w & 1, kh = (w >> 1) * 4;
        int n = n0 + g;
        u16x4 pv[3];
        #pragma unroll
        for (int d = 0; d < 3; ++d)
            pv[d] = *(const u16x4*)&Pbf[((b * 3 + d) * 4096 + n) * 256 + lane * 4];
        const int* idq = idxw + (b * 4096 + n) * 16 + kh;
        #pragma unroll
        for (int kk = 0; kk < 4; ++kk) {
            int m = idq[kk];                           // wave-uniform
            u16x4 qv = *(const u16x4*)&Qbf[(b * 4096 + m) * 256 + lane * 4];
            float q0 = bf2f(qv[0]), q1 = bf2f(qv[1]), q2 = bf2f(qv[2]), q3 = bf2f(qv[3]);
            #pragma unroll
            for (int d = 0; d < 3; ++d) {
                uint2v hv;
                hv[0] = pk2(fmaxf(bf2f(pv[d][0]) + q0, 0.f), fmaxf(bf2f(pv[d][1]) + q1, 0.f));
                hv[1] = pk2(fmaxf(bf2f(pv[d][2]) + q2, 0.f), fmaxf(bf2f(pv[d][3]) + q3, 0.f));
                *(uint2v*)&hL[g * 48 + d * 16 + kh + kk][lane * 4] = hv;
            }
        }
    }
    __syncthreads();

    // ---- layer 2: h2 = relu(W2 @ h1 + b2), 256 rows x 96 cols ----
    // wave w -> rows w*32 .. w*32+31 (2 row-tiles)
    f32x4 acc[2][6];
    #pragma unroll
    for (int i = 0; i < 2; ++i)
        #pragma unroll
        for (int jt = 0; jt < 6; ++jt)
            acc[i][jt] = (f32x4){0.f, 0.f, 0.f, 0.f};

    const u16* Arow = W2bf + (w * 32 + cl) * 256 + q * 8;
    for (int kt = 0; kt < 8; ++kt) {
        int k0 = kt * 32;
        bf16x8 a[2], bb[6];
        #pragma unroll
        for (int i = 0; i < 2; ++i)
            a[i] = *(const bf16x8*)(Arow + i * 4096 + k0);
        #pragma unroll
        for (int jt = 0; jt < 6; ++jt)
            bb[jt] = *(const bf16x8*)(&hL[jt * 16 + cl][k0 + q * 8]);
        #pragma unroll
        for (int i = 0; i < 2; ++i)
            #pragma unroll
            for (int jt = 0; jt < 6; ++jt)
                acc[i][jt] = __builtin_amdgcn_mfma_f32_16x16x32_bf16(a[i], bb[jt], acc[i][jt], 0, 0, 0);
    }
    __syncthreads();   // everyone done reading h1

    // write h2 (bf16) into the same LDS buffer; bias from L1
    #pragma unroll
    for (int i = 0; i < 2; ++i) {
        int rowb = w * 32 + i * 16 + q * 4;
        float4 bv = *(const float4*)(b2 + rowb);
        #pragma unroll
        for (int jt = 0; jt < 6; ++jt) {
            f32x4 v = acc[i][jt];
            uint2v hv;
            hv[0] = pk2(fmaxf(v[0] + bv.x, 0.f), fmaxf(v[1] + bv.y, 0.f));
            hv[1] = pk2(fmaxf(v[2] + bv.z, 0.f), fmaxf(v[3] + bv.w, 0.f));
            *(uint2v*)&hL[jt * 16 + cl][rowb] = hv;
        }
    }
    __syncthreads();

    // ---- layer 3: r = W3 @ h2 + b3, 64 rows x 96 cols ----
    // wave w -> rows (w&3)*16.., col-half jt0 = (w>>2)*3 (3 of 6 tiles)
    int rw = (w & 3) * 16, jt0 = (w >> 2) * 3;
    f32x4 acc3[3];
    #pragma unroll
    for (int jt = 0; jt < 3; ++jt) acc3[jt] = (f32x4){0.f, 0.f, 0.f, 0.f};

    const u16* A3row = W3bf + (rw + cl) * 256 + q * 8;
    for (int kt = 0; kt < 8; ++kt) {
        int k0 = kt * 32;
        bf16x8 a3 = *(const bf16x8*)(A3row + k0);
        #pragma unroll
        for (int jt = 0; jt < 3; ++jt) {
            bf16x8 bb = *(const bf16x8*)(&hL[(jt0 + jt) * 16 + cl][k0 + q * 8]);
            acc3[jt] = __builtin_amdgcn_mfma_f32_16x16x32_bf16(a3, bb, acc3[jt], 0, 0, 0);
        }
    }

    // ---- epilogue: +b3, max over k (16 cols of each tile = cl), +x, store ----
    int rowb = rw + q * 4;
    float4 b3v = *(const float4*)(b3 + rowb);
    #pragma unroll
    for (int jt = 0; jt < 3; ++jt) {
        int jj = jt0 + jt;
        int g = jj / 3, d = jj % 3;
        int n = n0 + g;
        f32x4 v = acc3[jt];
        v[0] += b3v.x;
        v[1] += b3v.y;
        v[2] += b3v.z;
        v[3] += b3v.w;
        #pragma unroll
        for (int off = 1; off < 16; off <<= 1) {
            v[0] = fmaxf(v[0], __shfl_xor(v[0], off));
            v[1] = fmaxf(v[1], __shfl_xor(v[1], off));
            v[2] = fmaxf(v[2], __shfl_xor(v[2], off));
            v[3] = fmaxf(v[3], __shfl_xor(v[3], off));
        }
        if (cl == 0) {
            #pragma unroll
            for (int r = 0; r < 4; ++r) {
                int addr = ((b * 64 + rowb + r) * 3 + d) * 4096 + n;
                out[addr] = v[r] + x[addr];
            }
        }
    }
}

extern "C" void kernel_launch(void* const* d_in, const int* in_sizes, int n_in,
                              void* d_out, int out_size, void* d_ws, size_t ws_size,
                              hipStream_t stream) {
    (void)in_sizes; (void)n_in; (void)out_size; (void)ws_size;
    const float* x  = (const float*)d_in[0];
    const float* W1 = (const float*)d_in[1];
    const float* b1 = (const float*)d_in[2];
    const float* W2 = (const float*)d_in[3];
    const float* b2 = (const float*)d_in[4];
    const float* W3 = (const float*)d_in[5];
    const float* b3 = (const float*)d_in[6];
    float* out = (float*)d_out;

    char* ws = (char*)d_ws;
    float* pc     = (float*)(ws + 0);          // 2,097,152 B  (B,C,N) fp32
    int*   idxw   = (int*)  (ws + 2129920);    //   524,288 B  (B,N,K)
    u16*   Qbf    = (u16*)  (ws + 2654208);    // 4,194,304 B  (B,N,H) bf16
    u16*   Pbf    = (u16*)  (ws + 6848512);    // 12,582,912 B (B,D,N,H) bf16
    u16*   W2bf   = (u16*)  (ws + 19431424);   //   131,072 B
    u16*   W3bf   = (u16*)  (ws + 19562496);   //    32,768 B
    u16*   W1dTbf = (u16*)  (ws + 19595264);   //    32,768 B  [h][c]
    u16*   W1bTbf = (u16*)  (ws + 19628032);   //    32,768 B  [h][c]
    u16*   xbf    = (u16*)  (ws + 19660800);   // 6,291,456 B  (B,C,D,N) bf16
    u16*   pcbf   = (u16*)  (ws + 25952256);   // 2,097,152 B  (B,C,N) bf16
    // KNN partials: pd fp32 (16,777,216 B) aliases Qbf+Pbf exactly (written by
    // knn_part, read by merge, BEFORE qp writes Qbf/Pbf). pi stored u16
    // (8,388,608 B) after pcbf; ends 36,438,016 < proven ws limit 36,503,552.
    float* pd     = (float*)(ws + 2654208);    // ends 19,431,424
    u16*   pi     = (u16*)  (ws + 28049408);   // ends 36,438,016

    mean_kernel<<<2048, 256, 0, stream>>>(x, pc, W1, W2, W3, W2bf, W3bf,
                                          W1dTbf, W1bTbf, xbf, pcbf);
    knn_part_kernel<<<1024, 256, 0, stream>>>(pc, pd, pi);
    knn_merge_kernel<<<2048, 256, 0, stream>>>(pd, pi, idxw);
    qp_mfma_kernel<<<512, 256, 0, stream>>>(xbf, pcbf, W1dTbf, W1bTbf, b1, Qbf, Pbf);
    fused_mlp_kernel<<<4096, 512, 0, stream>>>(x, Pbf, Qbf, idxw, W2bf, W3bf, b2, b3, out);
}